// Round 11
// baseline (339.760 us; speedup 1.0000x reference)
//
#include <hip/hip_runtime.h>
#include <math.h>

#define N_NODES 200000
#define N_EDGES 6400000
#define F_IN    128
#define H_HID   6
#define C_OUT   10
#define G_BATCH 64

#define TILE_E  8192                                 // edges per scatter tile
#define NT      ((N_EDGES + TILE_E - 1) / TILE_E)    // 782 tiles
#define EPT     16                                   // consecutive edges per thread
#define BSH     8                                    // bucket = col >> 8
#define BNODES  256                                  // nodes per bucket
#define NBUCK   ((N_NODES + BNODES - 1) / BNODES)    // 782 buckets
#define BCAP    9216                                 // slots/bucket (mean 8192, +11 sigma)
#define XBLK    512                                  // nodes per xw1acc block
#define NXB     ((N_NODES + XBLK - 1) / XBLK)        // 391

// ---- bf16 helpers (RNE) ---------------------------------------------------
__device__ __forceinline__ unsigned short f2bf(float f) {
    unsigned u = __float_as_uint(f);
    u += 0x7fff + ((u >> 16) & 1);
    return (unsigned short)(u >> 16);
}
__device__ __forceinline__ unsigned pack2(float a, float b) {
    return (unsigned)f2bf(a) | ((unsigned)f2bf(b) << 16);
}
__device__ __forceinline__ float bf_lo(unsigned u) { return __uint_as_float(u << 16); }
__device__ __forceinline__ float bf_hi(unsigned u) { return __uint_as_float(u & 0xffff0000u); }

// ---------------------------------------------------------------------------
// megaA: role-switched (round-6 structure). Blocks [0,NT): edge scatter into
// 782 FINE buckets (256 nodes each) — histogram/scan over 1024 entries via
// pair-scan (512 threads x 2 buckets). Blocks [NT,NT+NXB): xacc = x @ W1.
__global__ __launch_bounds__(512, 8) void megaA_kernel(const int* __restrict__ row,
                                                       const int* __restrict__ col,
                                                       const float* __restrict__ x,
                                                       const float* __restrict__ W1,
                                                       int* __restrict__ gcur,
                                                       int* __restrict__ binned,
                                                       float* __restrict__ xacc, int E) {
    __shared__ int sortbuf[TILE_E];   // 32 KB (xw1 role aliases first 3KB as W1 cache)
    __shared__ int cnt[1024];         // fine-bucket histogram, then placement cursor
    __shared__ int pos[1024];         // exclusive prefix (bucket -> tile-local start)
    __shared__ int lbase[1024];       // bucket -> global run base
    __shared__ int wtot[8];
    int tid = threadIdx.x;
    int bid = blockIdx.x;

    if (bid >= NT) {
        // ---- xw1acc role ----
        float* w = (float*)sortbuf;
        for (int i = tid; i < F_IN * H_HID; i += 512) w[i] = W1[i];
        __syncthreads();
        int n = (bid - NT) * XBLK + tid;
        if (n >= N_NODES) return;
        float acc[H_HID] = {0.f, 0.f, 0.f, 0.f, 0.f, 0.f};
        const float4* xr = (const float4*)(x + (size_t)n * F_IN);
#pragma unroll 4
        for (int f4 = 0; f4 < F_IN / 4; ++f4) {
            float4 v = xr[f4];
            int f = f4 * 4;
#pragma unroll
            for (int j = 0; j < H_HID; ++j) {
                acc[j] += v.x * w[(f + 0) * H_HID + j] + v.y * w[(f + 1) * H_HID + j]
                        + v.z * w[(f + 2) * H_HID + j] + v.w * w[(f + 3) * H_HID + j];
            }
        }
#pragma unroll
        for (int j = 0; j < H_HID; ++j) xacc[j * N_NODES + n] = acc[j];
        return;
    }

    // ---- scatter role ----
    int t = bid;
    int base = t * TILE_E;
    int tile_n = min(TILE_E, E - base);

    cnt[tid] = 0;
    cnt[tid + 512] = 0;
    __syncthreads();

    // phase 0: vector-load 16 consecutive edges, histogram fine buckets
    int myval[EPT];
    int myb[EPT];
    int ebase = base + tid * EPT;
    if (ebase + EPT <= E) {
        const int4* c4 = (const int4*)(col + ebase);
        const int4* r4 = (const int4*)(row + ebase);
#pragma unroll
        for (int q = 0; q < EPT / 4; ++q) {
            int4 c = c4[q];
            int4 r = r4[q];
            int k = q * 4;
            myval[k + 0] = ((c.x & (BNODES - 1)) << 18) | r.x;  myb[k + 0] = c.x >> BSH;
            myval[k + 1] = ((c.y & (BNODES - 1)) << 18) | r.y;  myb[k + 1] = c.y >> BSH;
            myval[k + 2] = ((c.z & (BNODES - 1)) << 18) | r.z;  myb[k + 2] = c.z >> BSH;
            myval[k + 3] = ((c.w & (BNODES - 1)) << 18) | r.w;  myb[k + 3] = c.w >> BSH;
        }
#pragma unroll
        for (int k = 0; k < EPT; ++k) atomicAdd(&cnt[myb[k]], 1);
    } else {
#pragma unroll
        for (int k = 0; k < EPT; ++k) {
            int e = ebase + k;
            if (e < E) {
                int c = col[e];
                myval[k] = ((c & (BNODES - 1)) << 18) | row[e];
                myb[k] = c >> BSH;
                atomicAdd(&cnt[myb[k]], 1);
            } else {
                myb[k] = -1;
            }
        }
    }
    __syncthreads();

    // phase 1: pair-scan of 1024 counts by 512 threads (3 barriers)
    int a0 = cnt[2 * tid], a1 = cnt[2 * tid + 1];
    int s = a0 + a1;
    int v = s;
    int lane = tid & 63, wid = tid >> 6;
#pragma unroll
    for (int off = 1; off < 64; off <<= 1) {
        int u = __shfl_up(v, off);
        if (lane >= off) v += u;
    }
    if (lane == 63) wtot[wid] = v;
    __syncthreads();
    if (tid == 0) {
        int running = 0;
#pragma unroll
        for (int i = 0; i < 8; ++i) { int w2 = wtot[i]; wtot[i] = running; running += w2; }
    }
    __syncthreads();
    {
        int pairExcl = v + wtot[wid] - s;       // sum of all entries before 2*tid
        pos[2 * tid] = pairExcl;
        pos[2 * tid + 1] = pairExcl + a0;
        cnt[2 * tid] = pairExcl;                // placement cursors
        cnt[2 * tid + 1] = pairExcl + a0;
        int b0 = 2 * tid, b1 = 2 * tid + 1;
        if (b0 < NBUCK) lbase[b0] = b0 * BCAP + (a0 ? atomicAdd(&gcur[b0], a0) : 0);
        if (b1 < NBUCK) lbase[b1] = b1 * BCAP + (a1 ? atomicAdd(&gcur[b1], a1) : 0);
    }
    __syncthreads();

    // phase 2: place into LDS sort buffer — pure LDS, no global loads
#pragma unroll
    for (int k = 0; k < EPT; ++k) {
        if (myb[k] >= 0) {
            int p = atomicAdd(&cnt[myb[k]], 1);
            sortbuf[p] = myval[k];
        }
    }
    __syncthreads();

    // phase 3: streaming write-out; position -> bucket via LDS binary search
    for (int i = tid; i < tile_n; i += 512) {
        int lo = 0, hi = NBUCK - 1;
        while (lo < hi) {
            int mid = (lo + hi + 1) >> 1;
            if (pos[mid] <= i) lo = mid; else hi = mid - 1;
        }
        binned[lbase[lo] + (i - pos[lo])] = sortbuf[i];
    }
}

// ---------------------------------------------------------------------------
// passB2: per-bucket degree histogram -> deg[] (for bg1/bg2 scans) and
// h1b = bf16-pack(d * xacc), d = rsqrt(deg+1). One binned sweep. 782 blocks.
__global__ __launch_bounds__(1024) void passB2_kernel(const int* __restrict__ gcur,
                                                      const int* __restrict__ binned,
                                                      const float* __restrict__ xacc,
                                                      int* __restrict__ deg,
                                                      uint4* __restrict__ h1b) {
    __shared__ int cnt[BNODES];
    int b = blockIdx.x, tid = threadIdx.x;
    int bb = b * BCAP, be = bb + gcur[b];
    if (tid < BNODES) cnt[tid] = 0;
    __syncthreads();
    int e = bb + tid;
    for (; e + 3072 < be; e += 4096) {
        int p0 = binned[e], p1 = binned[e + 1024], p2 = binned[e + 2048], p3 = binned[e + 3072];
        atomicAdd(&cnt[p0 >> 18], 1); atomicAdd(&cnt[p1 >> 18], 1);
        atomicAdd(&cnt[p2 >> 18], 1); atomicAdd(&cnt[p3 >> 18], 1);
    }
    for (; e < be; e += 1024) atomicAdd(&cnt[binned[e] >> 18], 1);
    __syncthreads();
    if (tid < BNODES) {
        int n = (b << BSH) + tid;
        if (n < N_NODES) {
            int dv = cnt[tid];
            deg[n] = dv;
            float d = rsqrtf((float)dv + 1.0f);
            float a0 = xacc[0 * N_NODES + n], a1 = xacc[1 * N_NODES + n];
            float a2 = xacc[2 * N_NODES + n], a3 = xacc[3 * N_NODES + n];
            float a4 = xacc[4 * N_NODES + n], a5 = xacc[5 * N_NODES + n];
            uint4 o;
            o.x = pack2(d * a0, d * a1);
            o.y = pack2(d * a2, d * a3);
            o.z = pack2(d * a4, d * a5);
            o.w = __float_as_uint(d);
            h1b[n] = o;
        }
    }
}

// ---- shfl scan of deg over 256 nodes (4 waves); INCL=0 -> exclusive
// offsets (cursors), INCL=1 -> inclusive ends (gather bounds). ----
#define DEG_SCAN(INCL)                                                          \
    {                                                                           \
        int n0 = (b << BSH) + tid;                                              \
        int v0 = (tid < BNODES && n0 < N_NODES) ? deg[n0] : 0;                  \
        int v = v0;                                                             \
        int lane = tid & 63, wid = tid >> 6;                                    \
        _Pragma("unroll")                                                       \
        for (int off = 1; off < 64; off <<= 1) {                                \
            int u = __shfl_up(v, off);                                          \
            if (lane >= off) v += u;                                            \
        }                                                                       \
        if (wid < 4 && lane == 63) wtot[wid] = v;                               \
        __syncthreads();                                                        \
        if (tid == 0) {                                                         \
            int running = 0;                                                    \
            _Pragma("unroll")                                                   \
            for (int i = 0; i < 4; ++i) { int w2 = wtot[i]; wtot[i] = running; running += w2; } \
        }                                                                       \
        __syncthreads();                                                        \
        if (tid < BNODES) cnt[tid] = v + wtot[wid] - (INCL ? 0 : v0);           \
    }                                                                           \
    __syncthreads();

#define GATHER_BODY(TBL)                                                        \
    float a[H_HID] = {0.f, 0.f, 0.f, 0.f, 0.f, 0.f};                            \
    {                                                                           \
        int ee = s + sub;                                                       \
        for (; ee + 24 < e_end; ee += 32) {                                     \
            int i0 = stage[ee], i1 = stage[ee + 8];                             \
            int i2 = stage[ee + 16], i3 = stage[ee + 24];                       \
            uint4 v0 = TBL[i0], v1 = TBL[i1], v2 = TBL[i2], v3 = TBL[i3];       \
            a[0] += (bf_lo(v0.x) + bf_lo(v1.x)) + (bf_lo(v2.x) + bf_lo(v3.x));  \
            a[1] += (bf_hi(v0.x) + bf_hi(v1.x)) + (bf_hi(v2.x) + bf_hi(v3.x));  \
            a[2] += (bf_lo(v0.y) + bf_lo(v1.y)) + (bf_lo(v2.y) + bf_lo(v3.y));  \
            a[3] += (bf_hi(v0.y) + bf_hi(v1.y)) + (bf_hi(v2.y) + bf_hi(v3.y));  \
            a[4] += (bf_lo(v0.z) + bf_lo(v1.z)) + (bf_lo(v2.z) + bf_lo(v3.z));  \
            a[5] += (bf_hi(v0.z) + bf_hi(v1.z)) + (bf_hi(v2.z) + bf_hi(v3.z));  \
        }                                                                       \
        for (; ee < e_end; ee += 8) {                                           \
            uint4 vv = TBL[stage[ee]];                                          \
            a[0] += bf_lo(vv.x); a[1] += bf_hi(vv.x);                           \
            a[2] += bf_lo(vv.y); a[3] += bf_hi(vv.y);                           \
            a[4] += bf_lo(vv.z); a[5] += bf_hi(vv.z);                           \
        }                                                                       \
    }                                                                           \
    _Pragma("unroll")                                                           \
    for (int j = 0; j < H_HID; ++j) {                                           \
        _Pragma("unroll")                                                       \
        for (int off = 4; off > 0; off >>= 1) a[j] += __shfl_xor(a[j], off);    \
    }

// ---------------------------------------------------------------------------
// bg1: deg-scan -> place (ONE binned sweep into LDS stage) -> publish csr
// (int4 coalesced) -> layer-1 gather -> rs. 782 blocks, 36.9KB LDS ->
// 2 blocks/CU by waves, all co-resident.
__global__ __launch_bounds__(1024) void bg1_kernel(const int* __restrict__ gcur,
                                                   const int* __restrict__ binned,
                                                   const int* __restrict__ deg,
                                                   const uint4* __restrict__ h1b,
                                                   const float* __restrict__ b1,
                                                   int* __restrict__ csr,
                                                   uint4* __restrict__ rs) {
    __shared__ int stage[BCAP];       // 36.9 KB
    __shared__ int cnt[BNODES];
    __shared__ int wtot[4];
    int b = blockIdx.x, tid = threadIdx.x;
    int bb = b * BCAP, be = bb + gcur[b];
    int total = be - bb;

    DEG_SCAN(0)                        // cnt = exclusive offsets (cursors)

    // place: single binned sweep
    {
        int e = bb + tid;
        for (; e + 3072 < be; e += 4096) {
            int p0 = binned[e], p1 = binned[e + 1024];
            int p2 = binned[e + 2048], p3 = binned[e + 3072];
            int s0 = atomicAdd(&cnt[p0 >> 18], 1); stage[s0] = p0 & 0x3FFFF;
            int s1 = atomicAdd(&cnt[p1 >> 18], 1); stage[s1] = p1 & 0x3FFFF;
            int s2 = atomicAdd(&cnt[p2 >> 18], 1); stage[s2] = p2 & 0x3FFFF;
            int s3 = atomicAdd(&cnt[p3 >> 18], 1); stage[s3] = p3 & 0x3FFFF;
        }
        for (; e < be; e += 1024) {
            int p = binned[e];
            int s = atomicAdd(&cnt[p >> 18], 1); stage[s] = p & 0x3FFFF;
        }
    }
    __syncthreads();                   // stage complete; cnt = end offsets

    // publish sorted run (coalesced int4 stores; overlap gather)
    for (int i = tid * 4; i + 3 < total; i += 4096)
        *(int4*)(csr + bb + i) = *(const int4*)(stage + i);
    {
        int b4 = total & ~3, r = total - b4;
        if (tid < r) csr[bb + b4 + tid] = stage[b4 + tid];
    }

    // layer-1 gather -> rs (2 chunks of 128 node-groups x 8 lanes)
    int sub = tid & 7, grp = tid >> 3;
    for (int ch = 0; ch < 2; ++ch) {
        int ln = ch * 128 + grp;
        int n = (b << BSH) + ln;
        int s = ln ? cnt[ln - 1] : 0;
        int e_end = cnt[ln];
        GATHER_BODY(h1b)
        if (sub == 0 && n < N_NODES) {
            uint4 self = h1b[n];
            float d = __uint_as_float(self.w);
            float sf[H_HID] = {bf_lo(self.x), bf_hi(self.x), bf_lo(self.y),
                               bf_hi(self.y), bf_lo(self.z), bf_hi(self.z)};
            float r[H_HID];
#pragma unroll
            for (int j = 0; j < H_HID; ++j) {
                float vv = d * (a[j] + sf[j]) + b1[j];
                r[j] = d * (vv > 0.f ? vv : 0.f);    // pre-scaled for layer 2
            }
            uint4 o;
            o.x = pack2(r[0], r[1]);
            o.y = pack2(r[2], r[3]);
            o.z = pack2(r[4], r[5]);
            o.w = self.w;
            rs[n] = o;
        }
    }
}

// ---------------------------------------------------------------------------
// bg2: deg-scan to run ends, int4-copy csr run into LDS (hides index latency
// under the gather), then layer-2 gather + W2 + hierarchical pool.
__global__ __launch_bounds__(1024) void bg2_kernel(const int* __restrict__ gcur,
                                                   const int* __restrict__ deg,
                                                   const int* __restrict__ csr,
                                                   const uint4* __restrict__ rs,
                                                   const float* __restrict__ W2,
                                                   const int* __restrict__ batch,
                                                   float* __restrict__ sums) {
    __shared__ int stage[BCAP];       // 36.9 KB
    __shared__ int cnt[BNODES];
    __shared__ int wtot[4];
    __shared__ float w2s[H_HID * C_OUT];
    __shared__ float nv[128][C_OUT + 1];
    __shared__ int lg[128];
    __shared__ float gacc[2][C_OUT];
    __shared__ int sg0;
    int b = blockIdx.x, tid = threadIdx.x;
    int bb = b * BCAP;
    int total = gcur[b];
    if (tid < H_HID * C_OUT) w2s[tid] = W2[tid];
    if (tid < 2 * C_OUT) ((float*)gacc)[tid] = 0.f;
    if (tid == 0) sg0 = batch[b << BSH];

    // copy csr run -> LDS (issue global loads early)
    for (int i = tid * 4; i + 3 < total; i += 4096)
        *(int4*)(stage + i) = *(const int4*)(csr + bb + i);
    {
        int b4 = total & ~3, r = total - b4;
        if (tid < r) stage[b4 + tid] = csr[bb + b4 + tid];
    }

    DEG_SCAN(1)                        // cnt = inclusive run ends (also fences copy)

    int sub = tid & 7, grp = tid >> 3;
    for (int ch = 0; ch < 2; ++ch) {
        int ln = ch * 128 + grp;
        int n = (b << BSH) + ln;
        int s = ln ? cnt[ln - 1] : 0;
        int e_end = cnt[ln];
        GATHER_BODY(rs)
        uint4 self = {0u, 0u, 0u, 0u};
        if (n < N_NODES) self = rs[n];
        float d = (n < N_NODES) ? __uint_as_float(self.w) : 0.f;
        float t[H_HID] = {a[0] + bf_lo(self.x), a[1] + bf_hi(self.x),
                          a[2] + bf_lo(self.y), a[3] + bf_hi(self.y),
                          a[4] + bf_lo(self.z), a[5] + bf_hi(self.z)};
        {
            float accv = 0.f;
#pragma unroll
            for (int j = 0; j < H_HID; ++j) accv += t[j] * w2s[j * C_OUT + sub];
            nv[grp][sub] = d * accv;
            if (sub < 2) {
                float accv2 = 0.f;
#pragma unroll
                for (int j = 0; j < H_HID; ++j) accv2 += t[j] * w2s[j * C_OUT + sub + 8];
                nv[grp][sub + 8] = d * accv2;
            }
        }
        if (sub == 0) lg[grp] = (n < N_NODES) ? batch[n] : sg0;
        __syncthreads();
        if (tid < 80) {
            int seg = tid / C_OUT, cc = tid - seg * C_OUT;
            int g = -1; float av = 0.f;
            for (int i = 0; i < 16; ++i) {
                int wdx = seg * 16 + i;
                int gw = lg[wdx];
                if (gw != g) {
                    if (g >= 0) {
                        int r2 = g - sg0;
                        if (r2 < 2) atomicAdd(&gacc[r2][cc], av);
                        else atomicAdd(&sums[g * C_OUT + cc], av);
                    }
                    g = gw; av = 0.f;
                }
                av += nv[wdx][cc];
            }
            int r2 = g - sg0;
            if (r2 < 2) atomicAdd(&gacc[r2][cc], av);
            else atomicAdd(&sums[g * C_OUT + cc], av);
        }
        __syncthreads();
    }
    if (tid < 2 * C_OUT) {
        int r2 = tid / C_OUT, cc = tid - r2 * C_OUT;
        int g = sg0 + r2;
        if (g < G_BATCH) atomicAdd(&sums[g * C_OUT + cc], gacc[r2][cc]);
    }
}

// mean (counts via binary search on sorted batch) + b2 + log_softmax
__global__ void pool_finish_kernel(const float* __restrict__ sums, const int* __restrict__ batch,
                                   const float* __restrict__ b2, float* __restrict__ out) {
    int g = threadIdx.x;
    if (g >= G_BATCH) return;
    int lo = 0, hi = N_NODES;
    while (lo < hi) { int mid = (lo + hi) >> 1; if (batch[mid] < g) lo = mid + 1; else hi = mid; }
    int c0 = lo;
    hi = N_NODES;
    while (lo < hi) { int mid = (lo + hi) >> 1; if (batch[mid] < g + 1) lo = mid + 1; else hi = mid; }
    float inv = 1.0f / fmaxf((float)(lo - c0), 1.0f);
    float v[C_OUT], m = -INFINITY;
#pragma unroll
    for (int c = 0; c < C_OUT; ++c) {
        v[c] = sums[g * C_OUT + c] * inv + b2[c];
        m = fmaxf(m, v[c]);
    }
    float s = 0.f;
#pragma unroll
    for (int c = 0; c < C_OUT; ++c) s += expf(v[c] - m);
    float lse = m + logf(s);
#pragma unroll
    for (int c = 0; c < C_OUT; ++c) out[g * C_OUT + c] = v[c] - lse;
}

extern "C" void kernel_launch(void* const* d_in, const int* in_sizes, int n_in,
                              void* d_out, int out_size, void* d_ws, size_t ws_size,
                              hipStream_t stream) {
    const float* x   = (const float*)d_in[0];
    const int* ei    = (const int*)d_in[1];
    const int* row   = ei;
    const int* col   = ei + N_EDGES;
    const int* batch = (const int*)d_in[2];
    const float* W1  = (const float*)d_in[3];
    const float* b1  = (const float*)d_in[4];
    const float* W2  = (const float*)d_in[5];
    const float* b2  = (const float*)d_in[6];
    float* out = (float*)d_out;

    // workspace layout — region sizes multiples of 16 B so uint4 arrays stay aligned
    char* p = (char*)d_ws;
    float* sums   = (float*)p;  p += (size_t)G_BATCH * C_OUT * 4;       // [zero] 2560B
    int*   gcur   = (int*)p;    p += (size_t)800 * 4;                   // [zero] 3200B (782 used)
    int*   deg    = (int*)p;    p += (size_t)N_NODES * 4;               // 800KB
    int*   binned = (int*)p;    p += (size_t)NBUCK * BCAP * 4;          // 28.8MB (gapped)
    int*   csr    = (int*)p;    p += (size_t)NBUCK * BCAP * 4;          // 28.8MB (gapped)
    float* xacc   = (float*)p;  p += (size_t)H_HID * N_NODES * 4;       // 4.8MB SoA
    uint4* h1b    = (uint4*)p;  p += (size_t)N_NODES * 16;              // 3.2MB
    uint4* rs     = (uint4*)p;                                          // 3.2MB

    hipMemsetAsync(sums, 0, (size_t)G_BATCH * C_OUT * 4 + 800 * 4, stream);   // sums + gcur

    megaA_kernel  <<<NT + NXB, 512, 0, stream>>>(row, col, x, W1, gcur, binned, xacc, N_EDGES);
    passB2_kernel <<<NBUCK, 1024, 0, stream>>>(gcur, binned, xacc, deg, h1b);
    bg1_kernel    <<<NBUCK, 1024, 0, stream>>>(gcur, binned, deg, h1b, b1, csr, rs);
    bg2_kernel    <<<NBUCK, 1024, 0, stream>>>(gcur, deg, csr, rs, W2, batch, sums);
    pool_finish_kernel<<<1, 64, 0, stream>>>(sums, batch, b2, out);
}

// Round 12
// 316.780 us; speedup vs baseline: 1.0725x; 1.0725x over previous
//
#include <hip/hip_runtime.h>
#include <math.h>

#define N_NODES 200000
#define N_EDGES 6400000
#define F_IN    128
#define H_HID   6
#define C_OUT   10
#define G_BATCH 64

#define TILE_E  8192                                 // edges per scatter tile
#define NT      ((N_EDGES + TILE_E - 1) / TILE_E)    // 782 tiles
#define EPT     16                                   // consecutive edges per thread
#define BSH     9                                    // bucket = col >> 9
#define BNODES  512                                  // nodes per bucket
#define NBUCK   ((N_NODES + BNODES - 1) / BNODES)    // 391 buckets
#define BCAP    17408                                // slots/bucket (mean 16384, +8 sigma)
#define XBLK    512                                  // nodes per xw1acc block
#define NXB     ((N_NODES + XBLK - 1) / XBLK)        // 391

// ---- bf16 helpers (RNE) ---------------------------------------------------
__device__ __forceinline__ unsigned short f2bf(float f) {
    unsigned u = __float_as_uint(f);
    u += 0x7fff + ((u >> 16) & 1);
    return (unsigned short)(u >> 16);
}
__device__ __forceinline__ unsigned pack2(float a, float b) {
    return (unsigned)f2bf(a) | ((unsigned)f2bf(b) << 16);
}
__device__ __forceinline__ float bf_lo(unsigned u) { return __uint_as_float(u << 16); }
__device__ __forceinline__ float bf_hi(unsigned u) { return __uint_as_float(u & 0xffff0000u); }

// ---------------------------------------------------------------------------
// megaA: role-switched. Blocks [0,NT): edge scatter. Blocks [NT,NT+NXB):
// xacc = x @ W1 (raw fp32, SoA). Appended role order (best measured: the
// xw1 stream overlaps the scatter's retirement tail, ~14 us).
__global__ __launch_bounds__(512, 8) void megaA_kernel(const int* __restrict__ row,
                                                       const int* __restrict__ col,
                                                       const float* __restrict__ x,
                                                       const float* __restrict__ W1,
                                                       int* __restrict__ gcur,
                                                       int* __restrict__ binned,
                                                       float* __restrict__ xacc, int E) {
    __shared__ int sortbuf[TILE_E];   // 32 KB (xw1 role aliases first 3KB as W1 cache)
    __shared__ int cnt[512];
    __shared__ int pos[513];
    __shared__ int lbase[512];
    __shared__ int wtot[8];
    int tid = threadIdx.x;

    if (blockIdx.x >= NT) {
        // ---- xw1acc role ----
        float* w = (float*)sortbuf;
        for (int i = tid; i < F_IN * H_HID; i += 512) w[i] = W1[i];
        __syncthreads();
        int n = (blockIdx.x - NT) * XBLK + tid;
        if (n >= N_NODES) return;
        float acc[H_HID] = {0.f, 0.f, 0.f, 0.f, 0.f, 0.f};
        const float4* xr = (const float4*)(x + (size_t)n * F_IN);
#pragma unroll 4
        for (int f4 = 0; f4 < F_IN / 4; ++f4) {
            float4 v = xr[f4];
            int f = f4 * 4;
#pragma unroll
            for (int j = 0; j < H_HID; ++j) {
                acc[j] += v.x * w[(f + 0) * H_HID + j] + v.y * w[(f + 1) * H_HID + j]
                        + v.z * w[(f + 2) * H_HID + j] + v.w * w[(f + 3) * H_HID + j];
            }
        }
#pragma unroll
        for (int j = 0; j < H_HID; ++j) xacc[j * N_NODES + n] = acc[j];
        return;
    }

    // ---- scatter role ----
    int t = blockIdx.x;
    int base = t * TILE_E;
    int tile_n = min(TILE_E, E - base);

    cnt[tid] = 0;
    __syncthreads();

    int myval[EPT];
    int myb[EPT];
    int ebase = base + tid * EPT;
    if (ebase + EPT <= E) {
        const int4* c4 = (const int4*)(col + ebase);
        const int4* r4 = (const int4*)(row + ebase);
#pragma unroll
        for (int q = 0; q < EPT / 4; ++q) {
            int4 c = c4[q];
            int4 r = r4[q];
            int k = q * 4;
            myval[k + 0] = ((c.x & (BNODES - 1)) << 18) | r.x;  myb[k + 0] = c.x >> BSH;
            myval[k + 1] = ((c.y & (BNODES - 1)) << 18) | r.y;  myb[k + 1] = c.y >> BSH;
            myval[k + 2] = ((c.z & (BNODES - 1)) << 18) | r.z;  myb[k + 2] = c.z >> BSH;
            myval[k + 3] = ((c.w & (BNODES - 1)) << 18) | r.w;  myb[k + 3] = c.w >> BSH;
        }
#pragma unroll
        for (int k = 0; k < EPT; ++k) atomicAdd(&cnt[myb[k]], 1);
    } else {
#pragma unroll
        for (int k = 0; k < EPT; ++k) {
            int e = ebase + k;
            if (e < E) {
                int c = col[e];
                myval[k] = ((c & (BNODES - 1)) << 18) | row[e];
                myb[k] = c >> BSH;
                atomicAdd(&cnt[myb[k]], 1);
            } else {
                myb[k] = -1;
            }
        }
    }
    __syncthreads();

    int c = cnt[tid];
    int v = c;
    int lane = tid & 63, wid = tid >> 6;
#pragma unroll
    for (int off = 1; off < 64; off <<= 1) {
        int u = __shfl_up(v, off);
        if (lane >= off) v += u;
    }
    if (lane == 63) wtot[wid] = v;
    __syncthreads();
    if (tid == 0) {
        int running = 0;
#pragma unroll
        for (int i = 0; i < 8; ++i) { int w2 = wtot[i]; wtot[i] = running; running += w2; }
    }
    __syncthreads();
    int incl = v + wtot[wid];
    int excl = incl - c;
    pos[tid] = excl;
    cnt[tid] = excl;
    if (tid == 511) pos[512] = incl;
    if (tid < NBUCK) {
        lbase[tid] = tid * BCAP + (c ? atomicAdd(&gcur[tid], c) : 0);
    }
    __syncthreads();

#pragma unroll
    for (int k = 0; k < EPT; ++k) {
        if (myb[k] >= 0) {
            int p = atomicAdd(&cnt[myb[k]], 1);
            sortbuf[p] = myval[k];
        }
    }
    __syncthreads();

    for (int i = tid; i < tile_n; i += 512) {
        int lo = 0, hi = NBUCK - 1;
        while (lo < hi) {
            int mid = (lo + hi + 1) >> 1;
            if (pos[mid] <= i) lo = mid; else hi = mid - 1;
        }
        binned[lbase[lo] + (i - pos[lo])] = sortbuf[i];
    }
}

// ---------------------------------------------------------------------------
// passB2: per-bucket degree histogram -> deg[] (for bg1/bg2 scans) and
// h1b = bf16-pack(d * xacc), d = rsqrt(deg+1). One binned sweep.
__global__ __launch_bounds__(1024) void passB2_kernel(const int* __restrict__ gcur,
                                                      const int* __restrict__ binned,
                                                      const float* __restrict__ xacc,
                                                      int* __restrict__ deg,
                                                      uint4* __restrict__ h1b) {
    __shared__ int cnt[512];
    int b = blockIdx.x, tid = threadIdx.x;
    int bb = b * BCAP, be = bb + gcur[b];
    if (tid < 512) cnt[tid] = 0;
    __syncthreads();
    int e = bb + tid;
    for (; e + 3072 < be; e += 4096) {
        int p0 = binned[e], p1 = binned[e + 1024], p2 = binned[e + 2048], p3 = binned[e + 3072];
        atomicAdd(&cnt[p0 >> 18], 1); atomicAdd(&cnt[p1 >> 18], 1);
        atomicAdd(&cnt[p2 >> 18], 1); atomicAdd(&cnt[p3 >> 18], 1);
    }
    for (; e < be; e += 1024) atomicAdd(&cnt[binned[e] >> 18], 1);
    __syncthreads();
    if (tid < 512) {
        int n = (b << BSH) + tid;
        if (n < N_NODES) {
            int dv = cnt[tid];
            deg[n] = dv;
            float d = rsqrtf((float)dv + 1.0f);
            float a0 = xacc[0 * N_NODES + n], a1 = xacc[1 * N_NODES + n];
            float a2 = xacc[2 * N_NODES + n], a3 = xacc[3 * N_NODES + n];
            float a4 = xacc[4 * N_NODES + n], a5 = xacc[5 * N_NODES + n];
            uint4 o;
            o.x = pack2(d * a0, d * a1);
            o.y = pack2(d * a2, d * a3);
            o.z = pack2(d * a4, d * a5);
            o.w = __float_as_uint(d);
            h1b[n] = o;
        }
    }
}

// ---- shfl scan of deg over 512 nodes; INCL=0 leaves exclusive offsets in
// cnt (placement cursors), INCL=1 leaves inclusive ends (gather bounds). ----
#define DEG_SCAN(INCL)                                                          \
    {                                                                           \
        int n0 = (b << BSH) + tid;                                              \
        int v0 = (tid < 512 && n0 < N_NODES) ? deg[n0] : 0;                     \
        int v = v0;                                                             \
        int lane = tid & 63, wid = tid >> 6;                                    \
        _Pragma("unroll")                                                       \
        for (int off = 1; off < 64; off <<= 1) {                                \
            int u = __shfl_up(v, off);                                          \
            if (lane >= off) v += u;                                            \
        }                                                                       \
        if (wid < 8 && lane == 63) wtot[wid] = v;                               \
        __syncthreads();                                                        \
        if (tid == 0) {                                                         \
            int running = 0;                                                    \
            _Pragma("unroll")                                                   \
            for (int i = 0; i < 8; ++i) { int w2 = wtot[i]; wtot[i] = running; running += w2; } \
        }                                                                       \
        __syncthreads();                                                        \
        if (tid < 512) cnt[tid] = v + wtot[wid] - (INCL ? 0 : v0);              \
    }                                                                           \
    __syncthreads();

#define GATHER_BODY(TBL)                                                        \
    float a[H_HID] = {0.f, 0.f, 0.f, 0.f, 0.f, 0.f};                            \
    {                                                                           \
        int ee = s + sub;                                                       \
        for (; ee + 24 < e_end; ee += 32) {                                     \
            int i0 = stage[ee], i1 = stage[ee + 8];                             \
            int i2 = stage[ee + 16], i3 = stage[ee + 24];                       \
            uint4 v0 = TBL[i0], v1 = TBL[i1], v2 = TBL[i2], v3 = TBL[i3];       \
            a[0] += (bf_lo(v0.x) + bf_lo(v1.x)) + (bf_lo(v2.x) + bf_lo(v3.x));  \
            a[1] += (bf_hi(v0.x) + bf_hi(v1.x)) + (bf_hi(v2.x) + bf_hi(v3.x));  \
            a[2] += (bf_lo(v0.y) + bf_lo(v1.y)) + (bf_lo(v2.y) + bf_lo(v3.y));  \
            a[3] += (bf_hi(v0.y) + bf_hi(v1.y)) + (bf_hi(v2.y) + bf_hi(v3.y));  \
            a[4] += (bf_lo(v0.z) + bf_lo(v1.z)) + (bf_lo(v2.z) + bf_lo(v3.z));  \
            a[5] += (bf_hi(v0.z) + bf_hi(v1.z)) + (bf_hi(v2.z) + bf_hi(v3.z));  \
        }                                                                       \
        for (; ee < e_end; ee += 8) {                                           \
            uint4 vv = TBL[stage[ee]];                                          \
            a[0] += bf_lo(vv.x); a[1] += bf_hi(vv.x);                           \
            a[2] += bf_lo(vv.y); a[3] += bf_hi(vv.y);                           \
            a[4] += bf_lo(vv.z); a[5] += bf_hi(vv.z);                           \
        }                                                                       \
    }                                                                           \
    _Pragma("unroll")                                                           \
    for (int j = 0; j < H_HID; ++j) {                                           \
        _Pragma("unroll")                                                       \
        for (int off = 4; off > 0; off >>= 1) a[j] += __shfl_xor(a[j], off);    \
    }

// ---------------------------------------------------------------------------
// bg1: deg-scan -> place (ONE binned sweep into LDS stage) -> publish csr
// (int4 coalesced) -> layer-1 gather -> rs.
__global__ __launch_bounds__(1024) void bg1_kernel(const int* __restrict__ gcur,
                                                   const int* __restrict__ binned,
                                                   const int* __restrict__ deg,
                                                   const uint4* __restrict__ h1b,
                                                   const float* __restrict__ b1,
                                                   int* __restrict__ csr,
                                                   uint4* __restrict__ rs) {
    __shared__ int stage[BCAP];       // 68 KB
    __shared__ int cnt[512];
    __shared__ int wtot[8];
    int b = blockIdx.x, tid = threadIdx.x;
    int bb = b * BCAP, be = bb + gcur[b];
    int total = be - bb;

    DEG_SCAN(0)                        // cnt = exclusive offsets (cursors)

    // place: single binned sweep
    {
        int e = bb + tid;
        for (; e + 3072 < be; e += 4096) {
            int p0 = binned[e], p1 = binned[e + 1024];
            int p2 = binned[e + 2048], p3 = binned[e + 3072];
            int s0 = atomicAdd(&cnt[p0 >> 18], 1); stage[s0] = p0 & 0x3FFFF;
            int s1 = atomicAdd(&cnt[p1 >> 18], 1); stage[s1] = p1 & 0x3FFFF;
            int s2 = atomicAdd(&cnt[p2 >> 18], 1); stage[s2] = p2 & 0x3FFFF;
            int s3 = atomicAdd(&cnt[p3 >> 18], 1); stage[s3] = p3 & 0x3FFFF;
        }
        for (; e < be; e += 1024) {
            int p = binned[e];
            int s = atomicAdd(&cnt[p >> 18], 1); stage[s] = p & 0x3FFFF;
        }
    }
    __syncthreads();                   // stage complete; cnt = end offsets

    // publish sorted run (coalesced int4 stores; overlap gather)
    for (int i = tid * 4; i + 3 < total; i += 4096)
        *(int4*)(csr + bb + i) = *(const int4*)(stage + i);
    {
        int b4 = total & ~3, r = total - b4;
        if (tid < r) csr[bb + b4 + tid] = stage[b4 + tid];
    }

    // layer-1 gather -> rs
    int sub = tid & 7, grp = tid >> 3;
    for (int ch = 0; ch < 4; ++ch) {
        int ln = ch * 128 + grp;
        int n = (b << BSH) + ln;
        int s = ln ? cnt[ln - 1] : 0;
        int e_end = cnt[ln];
        GATHER_BODY(h1b)
        if (sub == 0 && n < N_NODES) {
            uint4 self = h1b[n];
            float d = __uint_as_float(self.w);
            float sf[H_HID] = {bf_lo(self.x), bf_hi(self.x), bf_lo(self.y),
                               bf_hi(self.y), bf_lo(self.z), bf_hi(self.z)};
            float r[H_HID];
#pragma unroll
            for (int j = 0; j < H_HID; ++j) {
                float vv = d * (a[j] + sf[j]) + b1[j];
                r[j] = d * (vv > 0.f ? vv : 0.f);    // pre-scaled for layer 2
            }
            uint4 o;
            o.x = pack2(r[0], r[1]);
            o.y = pack2(r[2], r[3]);
            o.z = pack2(r[4], r[5]);
            o.w = self.w;
            rs[n] = o;
        }
    }
}

// ---------------------------------------------------------------------------
// bg2: deg-scan to run ends, int4-copy csr run into LDS (hides index latency
// under the gather), then layer-2 gather + W2 + hierarchical pool.
__global__ __launch_bounds__(1024) void bg2_kernel(const int* __restrict__ gcur,
                                                   const int* __restrict__ deg,
                                                   const int* __restrict__ csr,
                                                   const uint4* __restrict__ rs,
                                                   const float* __restrict__ W2,
                                                   const int* __restrict__ batch,
                                                   float* __restrict__ sums) {
    __shared__ int stage[BCAP];       // 68 KB
    __shared__ int cnt[512];
    __shared__ int wtot[8];
    __shared__ float w2s[H_HID * C_OUT];
    __shared__ float nv[128][C_OUT + 1];
    __shared__ int lg[128];
    __shared__ float gacc[2][C_OUT];
    __shared__ int sg0;
    int b = blockIdx.x, tid = threadIdx.x;
    int bb = b * BCAP;
    int total = gcur[b];
    if (tid < H_HID * C_OUT) w2s[tid] = W2[tid];
    if (tid < 2 * C_OUT) ((float*)gacc)[tid] = 0.f;
    if (tid == 0) sg0 = batch[b << BSH];

    // copy csr run -> LDS (issue global loads early)
    for (int i = tid * 4; i + 3 < total; i += 4096)
        *(int4*)(stage + i) = *(const int4*)(csr + bb + i);
    {
        int b4 = total & ~3, r = total - b4;
        if (tid < r) stage[b4 + tid] = csr[bb + b4 + tid];
    }

    DEG_SCAN(1)                        // cnt = inclusive run ends (also fences copy)

    int sub = tid & 7, grp = tid >> 3;
    for (int ch = 0; ch < 4; ++ch) {
        int ln = ch * 128 + grp;
        int n = (b << BSH) + ln;
        int s = ln ? cnt[ln - 1] : 0;
        int e_end = cnt[ln];
        GATHER_BODY(rs)
        uint4 self = {0u, 0u, 0u, 0u};
        if (n < N_NODES) self = rs[n];
        float d = (n < N_NODES) ? __uint_as_float(self.w) : 0.f;
        float t[H_HID] = {a[0] + bf_lo(self.x), a[1] + bf_hi(self.x),
                          a[2] + bf_lo(self.y), a[3] + bf_hi(self.y),
                          a[4] + bf_lo(self.z), a[5] + bf_hi(self.z)};
        {
            float accv = 0.f;
#pragma unroll
            for (int j = 0; j < H_HID; ++j) accv += t[j] * w2s[j * C_OUT + sub];
            nv[grp][sub] = d * accv;
            if (sub < 2) {
                float accv2 = 0.f;
#pragma unroll
                for (int j = 0; j < H_HID; ++j) accv2 += t[j] * w2s[j * C_OUT + sub + 8];
                nv[grp][sub + 8] = d * accv2;
            }
        }
        if (sub == 0) lg[grp] = (n < N_NODES) ? batch[n] : sg0;
        __syncthreads();
        if (tid < 80) {
            int seg = tid / C_OUT, cc = tid - seg * C_OUT;
            int g = -1; float av = 0.f;
            for (int i = 0; i < 16; ++i) {
                int wdx = seg * 16 + i;
                int gw = lg[wdx];
                if (gw != g) {
                    if (g >= 0) {
                        int r2 = g - sg0;
                        if (r2 < 2) atomicAdd(&gacc[r2][cc], av);
                        else atomicAdd(&sums[g * C_OUT + cc], av);
                    }
                    g = gw; av = 0.f;
                }
                av += nv[wdx][cc];
            }
            int r2 = g - sg0;
            if (r2 < 2) atomicAdd(&gacc[r2][cc], av);
            else atomicAdd(&sums[g * C_OUT + cc], av);
        }
        __syncthreads();
    }
    if (tid < 2 * C_OUT) {
        int r2 = tid / C_OUT, cc = tid - r2 * C_OUT;
        int g = sg0 + r2;
        if (g < G_BATCH) atomicAdd(&sums[g * C_OUT + cc], gacc[r2][cc]);
    }
}

// mean (counts via binary search on sorted batch) + b2 + log_softmax
__global__ void pool_finish_kernel(const float* __restrict__ sums, const int* __restrict__ batch,
                                   const float* __restrict__ b2, float* __restrict__ out) {
    int g = threadIdx.x;
    if (g >= G_BATCH) return;
    int lo = 0, hi = N_NODES;
    while (lo < hi) { int mid = (lo + hi) >> 1; if (batch[mid] < g) lo = mid + 1; else hi = mid; }
    int c0 = lo;
    hi = N_NODES;
    while (lo < hi) { int mid = (lo + hi) >> 1; if (batch[mid] < g + 1) lo = mid + 1; else hi = mid; }
    float inv = 1.0f / fmaxf((float)(lo - c0), 1.0f);
    float v[C_OUT], m = -INFINITY;
#pragma unroll
    for (int c = 0; c < C_OUT; ++c) {
        v[c] = sums[g * C_OUT + c] * inv + b2[c];
        m = fmaxf(m, v[c]);
    }
    float s = 0.f;
#pragma unroll
    for (int c = 0; c < C_OUT; ++c) s += expf(v[c] - m);
    float lse = m + logf(s);
#pragma unroll
    for (int c = 0; c < C_OUT; ++c) out[g * C_OUT + c] = v[c] - lse;
}

extern "C" void kernel_launch(void* const* d_in, const int* in_sizes, int n_in,
                              void* d_out, int out_size, void* d_ws, size_t ws_size,
                              hipStream_t stream) {
    const float* x   = (const float*)d_in[0];
    const int* ei    = (const int*)d_in[1];
    const int* row   = ei;
    const int* col   = ei + N_EDGES;
    const int* batch = (const int*)d_in[2];
    const float* W1  = (const float*)d_in[3];
    const float* b1  = (const float*)d_in[4];
    const float* W2  = (const float*)d_in[5];
    const float* b2  = (const float*)d_in[6];
    float* out = (float*)d_out;

    // workspace layout — region sizes multiples of 16 B so uint4 arrays stay aligned
    char* p = (char*)d_ws;
    float* sums   = (float*)p;  p += (size_t)G_BATCH * C_OUT * 4;       // [zero] 2560B
    int*   gcur   = (int*)p;    p += (size_t)400 * 4;                   // [zero] 1600B (391 used)
    int*   deg    = (int*)p;    p += (size_t)N_NODES * 4;               // 800KB
    int*   binned = (int*)p;    p += (size_t)NBUCK * BCAP * 4;          // 27.2MB (gapped)
    int*   csr    = (int*)p;    p += (size_t)NBUCK * BCAP * 4;          // 27.2MB (gapped)
    float* xacc   = (float*)p;  p += (size_t)H_HID * N_NODES * 4;       // 4.8MB SoA
    uint4* h1b    = (uint4*)p;  p += (size_t)N_NODES * 16;              // 3.2MB
    uint4* rs     = (uint4*)p;                                          // 3.2MB

    hipMemsetAsync(sums, 0, (size_t)G_BATCH * C_OUT * 4 + 400 * 4, stream);   // sums + gcur

    megaA_kernel  <<<NT + NXB, 512, 0, stream>>>(row, col, x, W1, gcur, binned, xacc, N_EDGES);
    passB2_kernel <<<NBUCK, 1024, 0, stream>>>(gcur, binned, xacc, deg, h1b);
    bg1_kernel    <<<NBUCK, 1024, 0, stream>>>(gcur, binned, deg, h1b, b1, csr, rs);
    bg2_kernel    <<<NBUCK, 1024, 0, stream>>>(gcur, deg, csr, rs, W2, batch, sums);
    pool_finish_kernel<<<1, 64, 0, stream>>>(sums, batch, b2, out);
}